// Round 9
// baseline (352.443 us; speedup 1.0000x reference)
//
#include <hip/hip_runtime.h>

// ---------------------------------------------------------------------------
// Types / helpers
// ---------------------------------------------------------------------------
typedef __bf16 bf16x8 __attribute__((ext_vector_type(8)));
typedef float  f32x4  __attribute__((ext_vector_type(4)));
typedef unsigned short ushort8 __attribute__((ext_vector_type(8)));

__device__ __forceinline__ unsigned short f2bf(float f) {
    unsigned u = __float_as_uint(f);
    u += 0x7FFFu + ((u >> 16) & 1u);   // round-to-nearest-even
    return (unsigned short)(u >> 16);
}

__device__ __forceinline__ f32x4 mfma16x16x32(bf16x8 a, bf16x8 b, f32x4 c) {
    return __builtin_amdgcn_mfma_f32_16x16x32_bf16(a, b, c, 0, 0, 0);
}

__device__ __forceinline__ bf16x8 ld8(const unsigned short* p) {
    return __builtin_bit_cast(bf16x8, *(const ushort8*)p);
}

// raw v_exp_f32 (exp2). Very negative input flushes to zero.
__device__ __forceinline__ float exp2_fast(float x) {
    float r; asm("v_exp_f32 %0, %1" : "=v"(r) : "v"(x)); return r;
}

// async global->LDS, 16B per lane. LDS dest = wave-uniform base + lane*16.
__device__ __forceinline__ void glds16(const unsigned short* g, unsigned short* l) {
    __builtin_amdgcn_global_load_lds(
        (const __attribute__((address_space(1))) void*)g,
        (__attribute__((address_space(3))) void*)l, 16, 0, 0);
}

__device__ __forceinline__ float gelu_tanh(float x) {
    const float c = 0.7978845608028654f;
    float z = c * (x + 0.044715f * x * x * x);
    float e = __expf(2.f * z);
    float th = 1.f - 2.f / (e + 1.f);   // tanh(z)
    return 0.5f * x * (1.f + th);
}

#define N_EMBD 768
#define SEQ    1024
#define NHEAD  12
#define HS     64
#define MROWS  8192           // B*T

// ---------------------------------------------------------------------------
// Transpose + cast fp32 [K,N] -> bf16 [N,K]
// ---------------------------------------------------------------------------
__global__ __launch_bounds__(256) void tcast_kernel(const float* __restrict__ in,
                                                    unsigned short* __restrict__ out,
                                                    int K, int N) {
    __shared__ float tile[32][33];
    int nb = blockIdx.x * 32, kb = blockIdx.y * 32;
    int tx = threadIdx.x, ty = threadIdx.y;   // 32 x 8
#pragma unroll
    for (int i = 0; i < 4; i++) {
        int k = kb + ty + i * 8;
        tile[ty + i * 8][tx] = in[(size_t)k * N + nb + tx];
    }
    __syncthreads();
#pragma unroll
    for (int i = 0; i < 4; i++) {
        int n = nb + ty + i * 8;
        out[(size_t)n * K + kb + tx] = f2bf(tile[tx][ty + i * 8]);
    }
}

// ---------------------------------------------------------------------------
// LayerNorm fp32 row -> bf16 row.  One 256-thread block per row (C=768).
// ---------------------------------------------------------------------------
__global__ __launch_bounds__(256) void ln_kernel(const float* __restrict__ x,
                                                 const float* __restrict__ g,
                                                 const float* __restrict__ b,
                                                 unsigned short* __restrict__ out) {
    int row = blockIdx.x;
    const float* xr = x + (size_t)row * N_EMBD;
    float v[3], s = 0.f, s2 = 0.f;
#pragma unroll
    for (int i = 0; i < 3; i++) {
        v[i] = xr[threadIdx.x + i * 256];
        s += v[i]; s2 += v[i] * v[i];
    }
#pragma unroll
    for (int m = 1; m < 64; m <<= 1) { s += __shfl_xor(s, m); s2 += __shfl_xor(s2, m); }
    __shared__ float ps[4], ps2[4];
    int wid = threadIdx.x >> 6;
    if ((threadIdx.x & 63) == 0) { ps[wid] = s; ps2[wid] = s2; }
    __syncthreads();
    s  = ps[0] + ps[1] + ps[2] + ps[3];
    s2 = ps2[0] + ps2[1] + ps2[2] + ps2[3];
    float mu  = s * (1.f / N_EMBD);
    float var = s2 * (1.f / N_EMBD) - mu * mu;
    float inv = rsqrtf(var + 1e-5f);
#pragma unroll
    for (int i = 0; i < 3; i++) {
        int c = threadIdx.x + i * 256;
        out[(size_t)row * N_EMBD + c] = f2bf((v[i] - mu) * inv * g[c] + b[c]);
    }
}

// ---------------------------------------------------------------------------
// GEMM: C[M,N] = A[M,K](bf16) @ B(bf16, stored as B^T [N,K]) + bias, epilogue.
// EPI 0: out bf16 = acc+bias ; EPI 1: out bf16 = gelu(acc+bias) ;
// EPI 2: out f32 = acc+bias+res
// Tile (WM*32) x 128, BK=64, 4 waves (2x2). T4 counted-vmcnt pipeline:
// 3 LDS buffers, depth-2 prefetch, per-iter {vmcnt(counted); s_barrier;
// stage(kt+2); compute(kt)} -- no vmcnt(0) drain in the main loop.
// Requires NT = K/64 to be a multiple of 3 (K in {768, 3072} -> 12, 48).
// XOR chunk swizzle both-sides; bijective XCD remap (grid % 8 == 0).
// ---------------------------------------------------------------------------
template <int EPI, int WM>
__global__ __launch_bounds__(256) void gemm_bt_kernel(
    const unsigned short* __restrict__ A, const unsigned short* __restrict__ BT,
    const float* __restrict__ bias, const float* __restrict__ res,
    float* __restrict__ outF, unsigned short* __restrict__ outB,
    int M, int N, int K) {
    constexpr int BM = WM * 32;
    constexpr int ASZ = BM * 64;        // ushorts per A buffer
    constexpr int BSZ = 128 * 64;       // ushorts per B buffer
    __shared__ __attribute__((aligned(16))) unsigned short As[3 * ASZ];
    __shared__ __attribute__((aligned(16))) unsigned short Bs[3 * BSZ];
    const int gx = gridDim.x;
    const int slot = blockIdx.y * gx + blockIdx.x;
    const int chunk = (gx * gridDim.y) >> 3;
    const int logical = (slot & 7) * chunk + (slot >> 3);
    const int m0 = (logical / gx) * BM, n0 = (logical % gx) * 128;
    const int t = threadIdx.x, lane = t & 63, wid = t >> 6;
    const int wr = wid >> 1, wc = wid & 1;

    f32x4 acc[WM][4] = {};

    const int rrow = lane & 15, g = lane >> 4;
    const int swz8 = (rrow & 7) << 3;       // XOR swizzle on read (ushort units)

    const int srow = t >> 3;
    const int scol = ((t & 7) ^ (srow & 7)) * 8;

    const int NT = K >> 6;                  // 12 or 48; NT % 3 == 0

    auto STAGE = [&](int kt, int buf) {
        const int kk = kt << 6;
#pragma unroll
        for (int i = 0; i < WM; i++)
            glds16(&A[(size_t)(m0 + i * 32 + srow) * K + kk + scol],
                   &As[buf * ASZ + i * 2048 + wid * 512]);
#pragma unroll
        for (int i = 0; i < 4; i++)
            glds16(&BT[(size_t)(n0 + i * 32 + srow) * K + kk + scol],
                   &Bs[buf * BSZ + i * 2048 + wid * 512]);
    };

    auto ITER = [&](int kt, int buf, int sbuf) {
        // wait only for stage(kt) (the oldest WM+4 loads); drain only at the tail
        if (kt == NT - 1) {
            asm volatile("s_waitcnt vmcnt(0)" ::: "memory");
        } else if constexpr (WM == 4) {
            asm volatile("s_waitcnt vmcnt(8)" ::: "memory");
        } else {
            asm volatile("s_waitcnt vmcnt(6)" ::: "memory");
        }
        __builtin_amdgcn_s_barrier();       // stage(kt) visible; compute(kt-1) done
        __builtin_amdgcn_sched_barrier(0);
        if (kt + 2 < NT) STAGE(kt + 2, sbuf);   // overwrites buf of compute(kt-1)
        const unsigned short* ab = &As[buf * ASZ];
        const unsigned short* bb = &Bs[buf * BSZ];
#pragma unroll
        for (int s = 0; s < 2; s++) {
            bf16x8 af[WM], bfr[4];
#pragma unroll
            for (int i = 0; i < WM; i++) {
                int row = wr * (WM * 16) + i * 16 + rrow;
                af[i] = ld8(&ab[row * 64 + ((((s << 2) | g) << 3) ^ swz8)]);
            }
#pragma unroll
            for (int j = 0; j < 4; j++) {
                int row = wc * 64 + j * 16 + rrow;
                bfr[j] = ld8(&bb[row * 64 + ((((s << 2) | g) << 3) ^ swz8)]);
            }
#pragma unroll
            for (int i = 0; i < WM; i++)
#pragma unroll
                for (int j = 0; j < 4; j++) acc[i][j] = mfma16x16x32(af[i], bfr[j], acc[i][j]);
        }
    };

    STAGE(0, 0);
    STAGE(1, 1);
    for (int kt3 = 0; kt3 < NT; kt3 += 3) {
        ITER(kt3,     0, 2);
        ITER(kt3 + 1, 1, 0);
        ITER(kt3 + 2, 2, 1);
    }

    const int crow = g * 4, ccol = rrow;
#pragma unroll
    for (int i = 0; i < WM; i++) {
        int gr0 = m0 + wr * (WM * 16) + i * 16 + crow;
#pragma unroll
        for (int j = 0; j < 4; j++) {
            int gc = n0 + wc * 64 + j * 16 + ccol;
            float bv = bias[gc];
#pragma unroll
            for (int r = 0; r < 4; r++) {
                int gr = gr0 + r;
                float v = acc[i][j][r] + bv;
                if constexpr (EPI == 1) v = gelu_tanh(v);
                if constexpr (EPI == 2) {
                    outF[(size_t)gr * N + gc] = v + res[(size_t)gr * N + gc];
                } else {
                    outB[(size_t)gr * N + gc] = f2bf(v);
                }
            }
        }
    }
}

// ---------------------------------------------------------------------------
// Causal flash attention (round-8 version). qkv bf16 [8192, 2304].
// Logical grid 768 = 8 pairings x 96 bh, XCD-remapped. 512 threads = 8 waves:
// waves 0-3 own q-tile 15-p, waves 4-7 own q-tile p; K/V staging shared.
// STATIC-MAX softmax: P = exp2(s*scale) unnormalized. MFMA row-sum. T5 setprio.
// ---------------------------------------------------------------------------
#define SCALE_LOG2E 0.18033688011112042f   // 0.125 * log2(e)

__device__ __forceinline__ void attn_tile(
    const unsigned short* Ks, const unsigned short* Vt, unsigned short* P,
    const bf16x8* qf, f32x4* yacc, float* lrow,
    int q0w, int kv0, bool masked, int lane)
{
    const int rrow = lane & 15, g = lane >> 4, kg8 = g * 8;
    const int qrb = q0w + g * 4;
    // ---- S = Q K^T; P = exp2(s) written immediately (no row-max dep) ----
#pragma unroll
    for (int ct = 0; ct < 4; ct++) {
        const int j = ct * 16 + rrow;
        const unsigned short* kr = &Ks[j * 64];
        f32x4 z = {};
        z = mfma16x16x32(qf[0], ld8(&kr[((g    ) ^ (j & 7)) * 8]), z);
        z = mfma16x16x32(qf[1], ld8(&kr[((g + 4) ^ (j & 7)) * 8]), z);
        const int jj = kv0 + j;
#pragma unroll
        for (int r = 0; r < 4; r++) {
            float v = z[r] * SCALE_LOG2E;
            if (masked && jj > qrb + r) v = -1e30f;
            const int q = g * 4 + r;
            P[q * 80 + (j ^ ((q & 7) << 3))] = f2bf(exp2_fast(v));
        }
    }
    asm volatile("s_waitcnt lgkmcnt(0)" ::: "memory");
    __builtin_amdgcn_sched_barrier(0);
    const int sw = (rrow & 7) << 3;
    bf16x8 pa0 = ld8(&P[rrow * 80 + ((kg8     ) ^ sw)]);
    bf16x8 pa1 = ld8(&P[rrow * 80 + ((kg8 + 32) ^ sw)]);
    // ---- row-sum via MFMA against ones; PV ----
    const bf16x8 vones = __builtin_bit_cast(bf16x8,
        (ushort8){0x3F80, 0x3F80, 0x3F80, 0x3F80, 0x3F80, 0x3F80, 0x3F80, 0x3F80});
    __builtin_amdgcn_s_setprio(1);
    f32x4 ss = {};
    ss = mfma16x16x32(pa0, vones, ss);
    ss = mfma16x16x32(pa1, vones, ss);
#pragma unroll
    for (int r = 0; r < 4; r++) lrow[r] += ss[r];
#pragma unroll
    for (int dt = 0; dt < 4; dt++) {
        const unsigned short* vr = &Vt[(dt * 16 + rrow) * 88];
        yacc[dt] = mfma16x16x32(pa0, ld8(&vr[kg8     ]), yacc[dt]);
        yacc[dt] = mfma16x16x32(pa1, ld8(&vr[kg8 + 32]), yacc[dt]);
    }
    __builtin_amdgcn_s_setprio(0);
}

__global__ __launch_bounds__(512, 6) void attn_kernel(const unsigned short* __restrict__ qkv,
                                                      unsigned short* __restrict__ yb) {
    // XCD remap over logical grid 768 (p fastest, then bh)
    const int slot = blockIdx.y * 8 + blockIdx.x;
    const int logical = (slot & 7) * 96 + (slot >> 3);
    const int p = logical & 7;                 // 0..7
    const int bh = logical >> 3;               // 0..95
    const int b = bh / NHEAD, h = bh % NHEAD;
    const int t = threadIdx.x, lane = t & 63, wid = t >> 6;   // wid 0..7
    const int half = wid >> 2, w4 = wid & 3;
    const int qt = half ? p : (15 - p);
    const int ntSelf = half ? (p + 1) : (16 - p);
    const int ntMax = 16 - p;                  // >= ntSelf always
    const int q0w = qt * 64 + w4 * 16;
    const int rrow = lane & 15, g = lane >> 4, kg8 = g * 8;

    __shared__ __attribute__((aligned(16))) unsigned short Ks[64 * 64];
    __shared__ __attribute__((aligned(16))) unsigned short Vt[64 * 88];
    __shared__ __attribute__((aligned(16))) unsigned short Ps[8][16 * 80];

    // Q fragments (A-operand): row = lane&15, k = (lane>>4)*8 + j
    bf16x8 qf[2];
    {
        size_t base = ((size_t)(b * SEQ + q0w + rrow)) * 2304 + h * HS;
        qf[0] = ld8(&qkv[base + kg8]);
        qf[1] = ld8(&qkv[base + 32 + kg8]);
    }

    f32x4 y[4] = {};
    float lrow[4] = {0.f, 0.f, 0.f, 0.f};

    // K staging: 512 chunks, thread owns chunk t. row = t>>3, swizzled col.
    const int kr0 = t >> 3;
    const int kc0 = ((t & 7) ^ (kr0 & 7)) * 8;
    // V staging: thread owns column d = t&63, kv rows (t>>6)*8 .. +7
    const int vd = t & 63, vk = (t >> 6) * 8;

    for (int tt = 0; tt < ntMax; tt++) {
        const int kv0 = tt * 64;
        __syncthreads();   // previous tile's LDS reads complete
        glds16(&qkv[((size_t)(b * SEQ + kv0 + kr0)) * 2304 + 768 + h * HS + kc0], &Ks[wid * 512]);
        ushort8 v8;
#pragma unroll
        for (int i = 0; i < 8; i++)
            v8[i] = qkv[((size_t)(b * SEQ + kv0 + vk + i)) * 2304 + 1536 + h * HS + vd];
        *(ushort8*)&Vt[vd * 88 + vk] = v8;
        __syncthreads();   // staging visible (drains vmcnt + lgkmcnt)

        if (tt < ntSelf)
            attn_tile(Ks, Vt, &Ps[wid][0], qf, y, lrow, q0w, kv0, tt == ntSelf - 1, lane);
    }

    // ---- write out: o = y / l (P was unnormalized exp2) ----
#pragma unroll
    for (int dt = 0; dt < 4; dt++)
#pragma unroll
        for (int r = 0; r < 4; r++) {
            int col = h * HS + dt * 16 + rrow;
            yb[((size_t)(b * SEQ + q0w + g * 4 + r)) * N_EMBD + col] = f2bf(y[dt][r] / lrow[r]);
        }
}

// ---------------------------------------------------------------------------
// Orchestration
// ---------------------------------------------------------------------------
extern "C" void kernel_launch(void* const* d_in, const int* in_sizes, int n_in,
                              void* d_out, int out_size, void* d_ws, size_t ws_size,
                              hipStream_t stream) {
    const float* x        = (const float*)d_in[0];
    const float* ln1_g    = (const float*)d_in[1];
    const float* ln1_b    = (const float*)d_in[2];
    const float* w_attn   = (const float*)d_in[3];
    const float* b_attn   = (const float*)d_in[4];
    const float* w_proj   = (const float*)d_in[5];
    const float* b_proj   = (const float*)d_in[6];
    const float* ln2_g    = (const float*)d_in[7];
    const float* ln2_b    = (const float*)d_in[8];
    const float* w_fc     = (const float*)d_in[9];
    const float* b_fc     = (const float*)d_in[10];
    const float* w_fcp    = (const float*)d_in[11];
    const float* b_fcp    = (const float*)d_in[12];
    float* out = (float*)d_out;

    // workspace carve (ushort elements)
    unsigned short* ws = (unsigned short*)d_ws;
    unsigned short* wT_attn = ws;                          // 2304*768
    unsigned short* wT_proj = wT_attn + 2304 * 768;        // 768*768
    unsigned short* wT_fc   = wT_proj + 768 * 768;         // 3072*768
    unsigned short* wT_fcp  = wT_fc   + 3072 * 768;        // 768*3072
    unsigned short* xb      = wT_fcp  + 768 * 3072;        // 8192*768 (ln1 out, later ln2 out)
    unsigned short* qkv     = xb      + (size_t)MROWS * 768;   // 8192*2304
    unsigned short* yb      = qkv     + (size_t)MROWS * 2304;  // 8192*768 (attn out)
    unsigned short* act     = qkv;    // 8192*3072 overlays qkv+yb (both dead by then)
    float* x2 = (float*)(yb + (size_t)MROWS * 768);        // 8192*768 fp32

    dim3 tb(32, 8);
    // weight transposes (fp32 [K,N] -> bf16 [N,K])
    tcast_kernel<<<dim3(2304 / 32, 768 / 32), tb, 0, stream>>>(w_attn, wT_attn, 768, 2304);
    tcast_kernel<<<dim3(768 / 32, 768 / 32),  tb, 0, stream>>>(w_proj, wT_proj, 768, 768);
    tcast_kernel<<<dim3(3072 / 32, 768 / 32), tb, 0, stream>>>(w_fc,   wT_fc,   768, 3072);
    tcast_kernel<<<dim3(768 / 32, 3072 / 32), tb, 0, stream>>>(w_fcp,  wT_fcp,  3072, 768);

    // ln1
    ln_kernel<<<MROWS, 256, 0, stream>>>(x, ln1_g, ln1_b, xb);
    // qkv = ln1(x) @ w_attn + b_attn
    gemm_bt_kernel<0, 4><<<dim3(2304 / 128, MROWS / 128), 256, 0, stream>>>(
        xb, wT_attn, b_attn, nullptr, nullptr, qkv, MROWS, 2304, 768);
    // attention (paired q-tiles, 8 waves, static-max softmax)
    attn_kernel<<<dim3(8, 96), 512, 0, stream>>>(qkv, yb);
    // x2 = attn_y @ w_proj + b_proj + x     (N=768: 64x128 tile -> 768 blocks)
    gemm_bt_kernel<2, 2><<<dim3(768 / 128, MROWS / 64), 256, 0, stream>>>(
        yb, wT_proj, b_proj, x, x2, nullptr, MROWS, 768, 768);
    // ln2
    ln_kernel<<<MROWS, 256, 0, stream>>>(x2, ln2_g, ln2_b, xb);
    // act = gelu(h2 @ w_fc + b_fc)
    gemm_bt_kernel<1, 4><<<dim3(3072 / 128, MROWS / 128), 256, 0, stream>>>(
        xb, wT_fc, b_fc, nullptr, nullptr, act, MROWS, 3072, 768);
    // out = act @ w_fc_proj + b_fc_proj + x2
    gemm_bt_kernel<2, 2><<<dim3(768 / 128, MROWS / 64), 256, 0, stream>>>(
        act, wT_fcp, b_fcp, x2, out, nullptr, MROWS, 768, 3072);
}

// Round 10
// 259.985 us; speedup vs baseline: 1.3556x; 1.3556x over previous
//
#include <hip/hip_runtime.h>

// ---------------------------------------------------------------------------
// Types / helpers
// ---------------------------------------------------------------------------
typedef __bf16 bf16x8 __attribute__((ext_vector_type(8)));
typedef float  f32x4  __attribute__((ext_vector_type(4)));
typedef unsigned short ushort8 __attribute__((ext_vector_type(8)));

__device__ __forceinline__ unsigned short f2bf(float f) {
    unsigned u = __float_as_uint(f);
    u += 0x7FFFu + ((u >> 16) & 1u);   // round-to-nearest-even
    return (unsigned short)(u >> 16);
}

__device__ __forceinline__ f32x4 mfma16x16x32(bf16x8 a, bf16x8 b, f32x4 c) {
    return __builtin_amdgcn_mfma_f32_16x16x32_bf16(a, b, c, 0, 0, 0);
}

__device__ __forceinline__ bf16x8 ld8(const unsigned short* p) {
    return __builtin_bit_cast(bf16x8, *(const ushort8*)p);
}

// raw v_exp_f32 (exp2). Very negative input flushes to zero.
__device__ __forceinline__ float exp2_fast(float x) {
    float r; asm("v_exp_f32 %0, %1" : "=v"(r) : "v"(x)); return r;
}

// async global->LDS, 16B per lane. LDS dest = wave-uniform base + lane*16.
__device__ __forceinline__ void glds16(const unsigned short* g, unsigned short* l) {
    __builtin_amdgcn_global_load_lds(
        (const __attribute__((address_space(1))) void*)g,
        (__attribute__((address_space(3))) void*)l, 16, 0, 0);
}

__device__ __forceinline__ float gelu_tanh(float x) {
    const float c = 0.7978845608028654f;
    float z = c * (x + 0.044715f * x * x * x);
    float e = __expf(2.f * z);
    float th = 1.f - 2.f / (e + 1.f);   // tanh(z)
    return 0.5f * x * (1.f + th);
}

#define N_EMBD 768
#define SEQ    1024
#define NHEAD  12
#define HS     64
#define MROWS  8192           // B*T

// ---------------------------------------------------------------------------
// Transpose + cast fp32 [K,N] -> bf16 [N,K]
// ---------------------------------------------------------------------------
__global__ __launch_bounds__(256) void tcast_kernel(const float* __restrict__ in,
                                                    unsigned short* __restrict__ out,
                                                    int K, int N) {
    __shared__ float tile[32][33];
    int nb = blockIdx.x * 32, kb = blockIdx.y * 32;
    int tx = threadIdx.x, ty = threadIdx.y;   // 32 x 8
#pragma unroll
    for (int i = 0; i < 4; i++) {
        int k = kb + ty + i * 8;
        tile[ty + i * 8][tx] = in[(size_t)k * N + nb + tx];
    }
    __syncthreads();
#pragma unroll
    for (int i = 0; i < 4; i++) {
        int n = nb + ty + i * 8;
        out[(size_t)n * K + kb + tx] = f2bf(tile[tx][ty + i * 8]);
    }
}

// ---------------------------------------------------------------------------
// LayerNorm fp32 row -> bf16 row.  One 256-thread block per row (C=768).
// ---------------------------------------------------------------------------
__global__ __launch_bounds__(256) void ln_kernel(const float* __restrict__ x,
                                                 const float* __restrict__ g,
                                                 const float* __restrict__ b,
                                                 unsigned short* __restrict__ out) {
    int row = blockIdx.x;
    const float* xr = x + (size_t)row * N_EMBD;
    float v[3], s = 0.f, s2 = 0.f;
#pragma unroll
    for (int i = 0; i < 3; i++) {
        v[i] = xr[threadIdx.x + i * 256];
        s += v[i]; s2 += v[i] * v[i];
    }
#pragma unroll
    for (int m = 1; m < 64; m <<= 1) { s += __shfl_xor(s, m); s2 += __shfl_xor(s2, m); }
    __shared__ float ps[4], ps2[4];
    int wid = threadIdx.x >> 6;
    if ((threadIdx.x & 63) == 0) { ps[wid] = s; ps2[wid] = s2; }
    __syncthreads();
    s  = ps[0] + ps[1] + ps[2] + ps[3];
    s2 = ps2[0] + ps2[1] + ps2[2] + ps2[3];
    float mu  = s * (1.f / N_EMBD);
    float var = s2 * (1.f / N_EMBD) - mu * mu;
    float inv = rsqrtf(var + 1e-5f);
#pragma unroll
    for (int i = 0; i < 3; i++) {
        int c = threadIdx.x + i * 256;
        out[(size_t)row * N_EMBD + c] = f2bf((v[i] - mu) * inv * g[c] + b[c]);
    }
}

// ---------------------------------------------------------------------------
// GEMM (round-8 proven version): C = A @ B^T + bias, epilogue.
// EPI 0: out bf16 = acc+bias ; EPI 1: out bf16 = gelu(acc+bias) ;
// EPI 2: out f32 = acc+bias+res
// Tile (WM*32) x 128, BK=64, 4 waves (2x2). 2-phase double-buffered pipeline,
// ONE barrier per K-step. XOR chunk swizzle both-sides; XCD remap.
// ---------------------------------------------------------------------------
template <int EPI, int WM>
__global__ __launch_bounds__(256) void gemm_bt_kernel(
    const unsigned short* __restrict__ A, const unsigned short* __restrict__ BT,
    const float* __restrict__ bias, const float* __restrict__ res,
    float* __restrict__ outF, unsigned short* __restrict__ outB,
    int M, int N, int K) {
    constexpr int BM = WM * 32;
    constexpr int ASZ = BM * 64;        // ushorts per A buffer
    constexpr int BSZ = 128 * 64;       // ushorts per B buffer
    __shared__ __attribute__((aligned(16))) unsigned short As[2 * ASZ];
    __shared__ __attribute__((aligned(16))) unsigned short Bs[2 * BSZ];
    const int gx = gridDim.x;
    const int slot = blockIdx.y * gx + blockIdx.x;
    const int chunk = (gx * gridDim.y) >> 3;
    const int logical = (slot & 7) * chunk + (slot >> 3);
    const int m0 = (logical / gx) * BM, n0 = (logical % gx) * 128;
    const int t = threadIdx.x, lane = t & 63, wid = t >> 6;
    const int wr = wid >> 1, wc = wid & 1;

    f32x4 acc[WM][4] = {};

    const int rrow = lane & 15, g = lane >> 4;
    const int swz8 = (rrow & 7) << 3;       // XOR swizzle on read (ushort units)

    const int srow = t >> 3;
    const int scol = ((t & 7) ^ (srow & 7)) * 8;

    const int NT = K >> 6;
    // prologue: stage tile 0 into buffer 0
#pragma unroll
    for (int i = 0; i < WM; i++)
        glds16(&A[(size_t)(m0 + i * 32 + srow) * K + scol], &As[i * 2048 + wid * 512]);
#pragma unroll
    for (int i = 0; i < 4; i++)
        glds16(&BT[(size_t)(n0 + i * 32 + srow) * K + scol], &Bs[i * 2048 + wid * 512]);
    __syncthreads();

    int cur = 0;
    for (int kt = 0; kt < NT; ++kt) {
        if (kt + 1 < NT) {
            const int kk = (kt + 1) << 6;
            const int nb = (cur ^ 1);
#pragma unroll
            for (int i = 0; i < WM; i++)
                glds16(&A[(size_t)(m0 + i * 32 + srow) * K + kk + scol],
                       &As[nb * ASZ + i * 2048 + wid * 512]);
#pragma unroll
            for (int i = 0; i < 4; i++)
                glds16(&BT[(size_t)(n0 + i * 32 + srow) * K + kk + scol],
                       &Bs[nb * BSZ + i * 2048 + wid * 512]);
        }
        const unsigned short* ab = &As[cur * ASZ];
        const unsigned short* bb = &Bs[cur * BSZ];
#pragma unroll
        for (int s = 0; s < 2; s++) {
            bf16x8 af[WM], bfr[4];
#pragma unroll
            for (int i = 0; i < WM; i++) {
                int row = wr * (WM * 16) + i * 16 + rrow;
                af[i] = ld8(&ab[row * 64 + ((((s << 2) | g) << 3) ^ swz8)]);
            }
#pragma unroll
            for (int j = 0; j < 4; j++) {
                int row = wc * 64 + j * 16 + rrow;
                bfr[j] = ld8(&bb[row * 64 + ((((s << 2) | g) << 3) ^ swz8)]);
            }
#pragma unroll
            for (int i = 0; i < WM; i++)
#pragma unroll
                for (int j = 0; j < 4; j++) acc[i][j] = mfma16x16x32(af[i], bfr[j], acc[i][j]);
        }
        __syncthreads();   // drains vmcnt (next tile's DMA, issued pre-compute)
        cur ^= 1;
    }

    const int crow = g * 4, ccol = rrow;
#pragma unroll
    for (int i = 0; i < WM; i++) {
        int gr0 = m0 + wr * (WM * 16) + i * 16 + crow;
#pragma unroll
        for (int j = 0; j < 4; j++) {
            int gc = n0 + wc * 64 + j * 16 + ccol;
            float bv = bias[gc];
#pragma unroll
            for (int r = 0; r < 4; r++) {
                int gr = gr0 + r;
                float v = acc[i][j][r] + bv;
                if constexpr (EPI == 1) v = gelu_tanh(v);
                if constexpr (EPI == 2) {
                    outF[(size_t)gr * N + gc] = v + res[(size_t)gr * N + gc];
                } else {
                    outB[(size_t)gr * N + gc] = f2bf(v);
                }
            }
        }
    }
}

// ---------------------------------------------------------------------------
// Causal flash attention v3. qkv bf16 [8192, 2304] (q|k|v blocks of 768).
// Logical grid 768 = 8 pairings x 96 bh, XCD-remapped. 256 threads = 4 waves;
// each wave owns rows wid*16 of BOTH paired q-tiles (p and 15-p) and REUSES
// the K/V fragment registers across the two tiles (halves DS fragment reads
// per unit work -- the measured bottleneck). STATIC-MAX softmax:
// P = exp2(s*scale) unnormalized. Row-sum via MFMA vs ones. T5 setprio.
// ---------------------------------------------------------------------------
#define SCALE_LOG2E 0.18033688011112042f   // 0.125 * log2(e)

__global__ __launch_bounds__(256, 4) void attn_kernel(const unsigned short* __restrict__ qkv,
                                                      unsigned short* __restrict__ yb) {
    // XCD remap over logical grid 768 (p fastest, then bh)
    const int slot = blockIdx.y * 8 + blockIdx.x;
    const int logical = (slot & 7) * 96 + (slot >> 3);
    const int p = logical & 7;                 // 0..7
    const int bh = logical >> 3;               // 0..95
    const int b = bh / NHEAD, h = bh % NHEAD;
    const int t = threadIdx.x, lane = t & 63, wid = t >> 6;   // wid 0..3
    const int q0A = p * 64 + wid * 16, q0B = (15 - p) * 64 + wid * 16;
    const int ntA = p + 1, ntB = 16 - p;       // ntB > ntA always (p <= 7)
    const int rrow = lane & 15, g = lane >> 4, kg8 = g * 8;

    __shared__ __attribute__((aligned(16))) unsigned short Ks[64 * 64];
    __shared__ __attribute__((aligned(16))) unsigned short Vt[64 * 88];
    __shared__ __attribute__((aligned(16))) unsigned short Ps[4][2][16 * 80];

    // Q fragments (A-operand): row = lane&15, k = (lane>>4)*8 + j
    bf16x8 qfA[2], qfB[2];
    {
        size_t baseA = ((size_t)(b * SEQ + q0A + rrow)) * 2304 + h * HS;
        qfA[0] = ld8(&qkv[baseA + kg8]);
        qfA[1] = ld8(&qkv[baseA + 32 + kg8]);
        size_t baseB = ((size_t)(b * SEQ + q0B + rrow)) * 2304 + h * HS;
        qfB[0] = ld8(&qkv[baseB + kg8]);
        qfB[1] = ld8(&qkv[baseB + 32 + kg8]);
    }

    f32x4 yA[4] = {}, yB[4] = {};
    float lA[4] = {0.f, 0.f, 0.f, 0.f}, lB[4] = {0.f, 0.f, 0.f, 0.f};

    // K staging: 512 16B chunks; thread owns chunks t and t+256.
    // chunk n: row = n>>3, stored col-chunk (n&7) holds source (n&7)^(row&7).
    const int kr0 = t >> 3, kr1 = kr0 + 32;
    const int kc0 = ((t & 7) ^ (kr0 & 7)) * 8;   // row+32 same mod 8
    // V staging: thread owns column d = t&63, kv rows (t>>6)*16 .. +15
    const int vd = t & 63, vk = (t >> 6) * 16;

    unsigned short* PB = &Ps[wid][0][0];
    unsigned short* PA = &Ps[wid][1][0];
    const bf16x8 vones = __builtin_bit_cast(bf16x8,
        (ushort8){0x3F80, 0x3F80, 0x3F80, 0x3F80, 0x3F80, 0x3F80, 0x3F80, 0x3F80});

    for (int tt = 0; tt < ntB; tt++) {
        const int kv0 = tt * 64;
        const bool doA = (tt < ntA);
        const bool maskB = (tt == ntB - 1), maskA = (tt == ntA - 1);
        __syncthreads();   // previous tile's LDS reads complete
        glds16(&qkv[((size_t)(b * SEQ + kv0 + kr0)) * 2304 + 768 + h * HS + kc0], &Ks[wid * 512]);
        glds16(&qkv[((size_t)(b * SEQ + kv0 + kr1)) * 2304 + 768 + h * HS + kc0], &Ks[2048 + wid * 512]);
        ushort8 vlo, vhi;
#pragma unroll
        for (int i = 0; i < 8; i++)
            vlo[i] = qkv[((size_t)(b * SEQ + kv0 + vk + i)) * 2304 + 1536 + h * HS + vd];
#pragma unroll
        for (int i = 0; i < 8; i++)
            vhi[i] = qkv[((size_t)(b * SEQ + kv0 + vk + 8 + i)) * 2304 + 1536 + h * HS + vd];
        *(ushort8*)&Vt[vd * 88 + vk] = vlo;
        *(ushort8*)&Vt[vd * 88 + vk + 8] = vhi;
        __syncthreads();   // staging visible (drains vmcnt + lgkmcnt)

        // ---- S = Q K^T for BOTH tiles, sharing K fragment reads ----
        f32x4 sB[4], sA[4];
#pragma unroll
        for (int ct = 0; ct < 4; ct++) {
            const int j = ct * 16 + rrow;
            const unsigned short* kr = &Ks[j * 64];
            bf16x8 k0 = ld8(&kr[((g    ) ^ (j & 7)) * 8]);
            bf16x8 k1 = ld8(&kr[((g + 4) ^ (j & 7)) * 8]);
            f32x4 zB = {};
            zB = mfma16x16x32(qfB[0], k0, zB);
            zB = mfma16x16x32(qfB[1], k1, zB);
            sB[ct] = zB;
            if (doA) {
                f32x4 zA = {};
                zA = mfma16x16x32(qfA[0], k0, zA);
                zA = mfma16x16x32(qfA[1], k1, zA);
                sA[ct] = zA;
            }
        }
        // ---- P = exp2(s*scale) -> LDS (XOR-swizzled by q), both tiles ----
        const int qrbB = q0B + g * 4, qrbA = q0A + g * 4;
#pragma unroll
        for (int ct = 0; ct < 4; ct++) {
            const int j = ct * 16 + rrow, jj = kv0 + j;
#pragma unroll
            for (int r = 0; r < 4; r++) {
                float v = sB[ct][r] * SCALE_LOG2E;
                if (maskB && jj > qrbB + r) v = -1e30f;
                const int q = g * 4 + r;
                PB[q * 80 + (j ^ ((q & 7) << 3))] = f2bf(exp2_fast(v));
            }
        }
        if (doA) {
#pragma unroll
            for (int ct = 0; ct < 4; ct++) {
                const int j = ct * 16 + rrow, jj = kv0 + j;
#pragma unroll
                for (int r = 0; r < 4; r++) {
                    float v = sA[ct][r] * SCALE_LOG2E;
                    if (maskA && jj > qrbA + r) v = -1e30f;
                    const int q = g * 4 + r;
                    PA[q * 80 + (j ^ ((q & 7) << 3))] = f2bf(exp2_fast(v));
                }
            }
        }
        asm volatile("s_waitcnt lgkmcnt(0)" ::: "memory");
        __builtin_amdgcn_sched_barrier(0);
        const int sw = (rrow & 7) << 3;
        bf16x8 paB0 = ld8(&PB[rrow * 80 + ((kg8     ) ^ sw)]);
        bf16x8 paB1 = ld8(&PB[rrow * 80 + ((kg8 + 32) ^ sw)]);
        bf16x8 paA0, paA1;
        if (doA) {
            paA0 = ld8(&PA[rrow * 80 + ((kg8     ) ^ sw)]);
            paA1 = ld8(&PA[rrow * 80 + ((kg8 + 32) ^ sw)]);
        }
        // ---- row-sums via MFMA vs ones; PV for both tiles sharing V reads ----
        __builtin_amdgcn_s_setprio(1);
        f32x4 ssB = {};
        ssB = mfma16x16x32(paB0, vones, ssB);
        ssB = mfma16x16x32(paB1, vones, ssB);
#pragma unroll
        for (int r = 0; r < 4; r++) lB[r] += ssB[r];
        if (doA) {
            f32x4 ssA = {};
            ssA = mfma16x16x32(paA0, vones, ssA);
            ssA = mfma16x16x32(paA1, vones, ssA);
#pragma unroll
            for (int r = 0; r < 4; r++) lA[r] += ssA[r];
        }
#pragma unroll
        for (int dt = 0; dt < 4; dt++) {
            const unsigned short* vr = &Vt[(dt * 16 + rrow) * 88];
            bf16x8 v0 = ld8(&vr[kg8]);
            bf16x8 v1 = ld8(&vr[kg8 + 32]);
            yB[dt] = mfma16x16x32(paB0, v0, yB[dt]);
            yB[dt] = mfma16x16x32(paB1, v1, yB[dt]);
            if (doA) {
                yA[dt] = mfma16x16x32(paA0, v0, yA[dt]);
                yA[dt] = mfma16x16x32(paA1, v1, yA[dt]);
            }
        }
        __builtin_amdgcn_s_setprio(0);
    }

    // ---- write out both q-tiles: o = y / l ----
#pragma unroll
    for (int dt = 0; dt < 4; dt++)
#pragma unroll
        for (int r = 0; r < 4; r++) {
            int col = h * HS + dt * 16 + rrow;
            yb[((size_t)(b * SEQ + q0B + g * 4 + r)) * N_EMBD + col] = f2bf(yB[dt][r] / lB[r]);
            yb[((size_t)(b * SEQ + q0A + g * 4 + r)) * N_EMBD + col] = f2bf(yA[dt][r] / lA[r]);
        }
}

// ---------------------------------------------------------------------------
// Orchestration
// ---------------------------------------------------------------------------
extern "C" void kernel_launch(void* const* d_in, const int* in_sizes, int n_in,
                              void* d_out, int out_size, void* d_ws, size_t ws_size,
                              hipStream_t stream) {
    const float* x        = (const float*)d_in[0];
    const float* ln1_g    = (const float*)d_in[1];
    const float* ln1_b    = (const float*)d_in[2];
    const float* w_attn   = (const float*)d_in[3];
    const float* b_attn   = (const float*)d_in[4];
    const float* w_proj   = (const float*)d_in[5];
    const float* b_proj   = (const float*)d_in[6];
    const float* ln2_g    = (const float*)d_in[7];
    const float* ln2_b    = (const float*)d_in[8];
    const float* w_fc     = (const float*)d_in[9];
    const float* b_fc     = (const float*)d_in[10];
    const float* w_fcp    = (const float*)d_in[11];
    const float* b_fcp    = (const float*)d_in[12];
    float* out = (float*)d_out;

    // workspace carve (ushort elements)
    unsigned short* ws = (unsigned short*)d_ws;
    unsigned short* wT_attn = ws;                          // 2304*768
    unsigned short* wT_proj = wT_attn + 2304 * 768;        // 768*768
    unsigned short* wT_fc   = wT_proj + 768 * 768;         // 3072*768
    unsigned short* wT_fcp  = wT_fc   + 3072 * 768;        // 768*3072
    unsigned short* xb      = wT_fcp  + 768 * 3072;        // 8192*768 (ln1 out, later ln2 out)
    unsigned short* qkv     = xb      + (size_t)MROWS * 768;   // 8192*2304
    unsigned short* yb      = qkv     + (size_t)MROWS * 2304;  // 8192*768 (attn out)
    unsigned short* act     = qkv;    // 8192*3072 overlays qkv+yb (both dead by then)
    float* x2 = (float*)(yb + (size_t)MROWS * 768);        // 8192*768 fp32

    dim3 tb(32, 8);
    // weight transposes (fp32 [K,N] -> bf16 [N,K])
    tcast_kernel<<<dim3(2304 / 32, 768 / 32), tb, 0, stream>>>(w_attn, wT_attn, 768, 2304);
    tcast_kernel<<<dim3(768 / 32, 768 / 32),  tb, 0, stream>>>(w_proj, wT_proj, 768, 768);
    tcast_kernel<<<dim3(3072 / 32, 768 / 32), tb, 0, stream>>>(w_fc,   wT_fc,   768, 3072);
    tcast_kernel<<<dim3(768 / 32, 3072 / 32), tb, 0, stream>>>(w_fcp,  wT_fcp,  3072, 768);

    // ln1
    ln_kernel<<<MROWS, 256, 0, stream>>>(x, ln1_g, ln1_b, xb);
    // qkv = ln1(x) @ w_attn + b_attn
    gemm_bt_kernel<0, 4><<<dim3(2304 / 128, MROWS / 128), 256, 0, stream>>>(
        xb, wT_attn, b_attn, nullptr, nullptr, qkv, MROWS, 2304, 768);
    // attention (paired q-tiles, 4 waves, dual-tile fragment reuse)
    attn_kernel<<<dim3(8, 96), 256, 0, stream>>>(qkv, yb);
    // x2 = attn_y @ w_proj + b_proj + x     (N=768: 64x128 tile -> 768 blocks)
    gemm_bt_kernel<2, 2><<<dim3(768 / 128, MROWS / 64), 256, 0, stream>>>(
        yb, wT_proj, b_proj, x, x2, nullptr, MROWS, 768, 768);
    // ln2
    ln_kernel<<<MROWS, 256, 0, stream>>>(x2, ln2_g, ln2_b, xb);
    // act = gelu(h2 @ w_fc + b_fc)
    gemm_bt_kernel<1, 4><<<dim3(3072 / 128, MROWS / 128), 256, 0, stream>>>(
        xb, wT_fc, b_fc, nullptr, nullptr, act, MROWS, 3072, 768);
    // out = act @ w_fc_proj + b_fc_proj + x2
    gemm_bt_kernel<2, 2><<<dim3(768 / 128, MROWS / 64), 256, 0, stream>>>(
        act, wT_fcp, b_fcp, x2, out, nullptr, MROWS, 768, 3072);
}